// Round 3
// baseline (3666.270 us; speedup 1.0000x reference)
//
#include <hip/hip_runtime.h>

// ===== config =====
#define INPUTS_BF16 0   // inputs are fp32 per reference (NaN evidence round 1)
#define OUT_BF16    0   // reference output dtype is float32

typedef unsigned int  u32;
typedef unsigned short u16;
typedef unsigned long long u64;
typedef short bf16x8 __attribute__((ext_vector_type(8)));
typedef float f32x4  __attribute__((ext_vector_type(4)));
typedef unsigned int u32x4 __attribute__((ext_vector_type(4)));

// ---- bf16 helpers ----
__device__ __forceinline__ float bf2f(u16 x) {
  return __uint_as_float(((u32)x) << 16);
}
__device__ __forceinline__ u16 f2bf(float f) {
  u32 u = __float_as_uint(f);
  u += 0x7fffu + ((u >> 16) & 1u);   // RNE
  return (u16)(u >> 16);
}

// two table elements (pair idx2) -> packed bf16 pair
__device__ __forceinline__ u32 tload2(const void* tab, long idx2) {
#if INPUTS_BF16
  return ((const u32*)tab)[idx2];
#else
  float2 v = ((const float2*)tab)[idx2];
  return (u32)f2bf(v.x) | ((u32)f2bf(v.y) << 16);
#endif
}
__device__ __forceinline__ u16 wload(const void* w, long idx) {
#if INPUTS_BF16
  return ((const u16*)w)[idx];
#else
  return f2bf(((const float*)w)[idx]);
#endif
}
__device__ __forceinline__ float wloadf(const void* w, long idx) {
#if INPUTS_BF16
  return bf2f(((const u16*)w)[idx]);
#else
  return ((const float*)w)[idx];
#endif
}

// ---- fence-free coherent access (relaxed agent atomics: sc0/sc1, NO wbl2/inv) ----
__device__ __forceinline__ u32 aload32(const u32* p) {
  return __hip_atomic_load(p, __ATOMIC_RELAXED, __HIP_MEMORY_SCOPE_AGENT);
}
__device__ __forceinline__ u64 aload64(const u64* p) {
  return __hip_atomic_load(p, __ATOMIC_RELAXED, __HIP_MEMORY_SCOPE_AGENT);
}
__device__ __forceinline__ void astore32(u32* p, u32 v) {
  __hip_atomic_store(p, v, __ATOMIC_RELAXED, __HIP_MEMORY_SCOPE_AGENT);
}

// async global->LDS, 16B per lane; lds ptr must be wave-uniform (HW: base + lane*16)
__device__ __forceinline__ void async16(const u16* g, const u16* lds) {
  __builtin_amdgcn_global_load_lds((const __attribute__((address_space(1))) void*)g,
                                   (__attribute__((address_space(3))) void*)lds, 16, 0, 0);
}

// ===== problem constants =====
#define Bb   64
#define Ss   512
#define BS   32768           // B*S
#define KPAD 896             // 850 padded to mult of 64
#define HID  512
#define G4   2048            // 4*RNN_H

// ===== ws layout (bytes) =====
#define OFF_CAT   0ull                               // 2*BS*896 bf16   = 117,440,512
#define OFF_WLIN  117440512ull                       // 512*896 bf16
#define OFF_WIH   118358016ull                       // 2*2048*512 bf16
#define OFF_WHH   122552320ull
#define OFF_B4    126746624ull                       // 2*2048 f32
#define OFF_IN    126763008ull                       // 2*BS*512 bf16
#define OFF_XG    193871872ull                       // 2*512*64*2048 bf16
#define OFF_HBUF  462307328ull                       // 2dir*2par*64*512 bf16
#define OFF_CNT   462831616ull                       // flag slots (u32), region = 4KB
#define WS_NEED   462835712ull

// ======================= prep: pad/reorder weights, zero flags =======================
__global__ __launch_bounds__(256) void k_prep(
    const void* Wlin_in,
    const void* Wihl, const void* Whhl, const void* bihl, const void* bhhl,
    const void* Wihr, const void* Whhr, const void* bihr, const void* bhhr,
    u16* __restrict__ Wlin, u16* __restrict__ Wih, u16* __restrict__ Whh,
    float* __restrict__ b4, u16* __restrict__ hbuf, u32* __restrict__ cnt) {
  int i = blockIdx.x * 256 + threadIdx.x;
  const int N1 = 512 * KPAD;
  const int N2 = N1 + 2 * G4 * HID;
  const int N3 = N2 + 2 * G4 * HID;
  const int N4 = N3 + 2 * G4;
  const int N5 = N4 + 2 * 2 * Bb * HID;
  const int N6 = N5 + 1024;
  if (i < N1) {
    int n = i / KPAD, k = i - n * KPAD;
    Wlin[i] = (k < 850) ? wload(Wlin_in, (long)n * 850 + k) : (u16)0;
  } else if (i < N2) {
    int j = i - N1;
    int dir = j >> 20;                 // 2048*512 = 1<<20
    int rem = j & ((1 << 20) - 1);
    int np_ = rem >> 9, k = rem & 511;
    int orig = (np_ & 3) * 512 + (np_ >> 2);   // n' = 4j+g  ->  orig row g*512+j
    Wih[j] = wload(dir ? Wihr : Wihl, (long)orig * 512 + k);
  } else if (i < N3) {
    int j = i - N2;
    int dir = j >> 20;
    int rem = j & ((1 << 20) - 1);
    int np_ = rem >> 9, k = rem & 511;
    int orig = (np_ & 3) * 512 + (np_ >> 2);
    Whh[j] = wload(dir ? Whhr : Whhl, (long)orig * 512 + k);
  } else if (i < N4) {
    int j = i - N3;
    int dir = j >> 11, np_ = j & 2047;
    int orig = (np_ & 3) * 512 + (np_ >> 2);
    b4[j] = wloadf(dir ? bihr : bihl, orig) + wloadf(dir ? bhhr : bhhl, orig);
  } else if (i < N5) {
    hbuf[i - N4] = 0;
  } else if (i < N6) {
    cnt[i - N5] = 0;
  }
}

// ======================= gather/concat -> cat[2][BS][896] bf16 =======================
__global__ __launch_bounds__(256) void k_gather(
    const int* __restrict__ ci, const int* __restrict__ cti,
    const int* __restrict__ lbi, const int* __restrict__ rbi,
    const int* __restrict__ eci, const int* __restrict__ lebi, const int* __restrict__ rebi,
    const void* __restrict__ charE, const void* __restrict__ ctypeE,
    const void* __restrict__ biE, const void* __restrict__ extE, const void* __restrict__ extbiE,
    u32* __restrict__ cat) {
  int p = blockIdx.x;
  int t = threadIdx.x;
  u32* L = cat + (size_t)p * 448;             // 896 bf16 = 448 u32
  u32* R = cat + (size_t)(BS + p) * 448;
  long c0 = (long)ci[p] * 100,  e0 = (long)eci[p] * 100;   // pair units (row=200 f32 = 100 pairs)
  long lb0 = (long)lbi[p] * 100, rb0 = (long)rbi[p] * 100;
  long le0 = (long)lebi[p] * 100, re0 = (long)rebi[p] * 100;
  long ct0 = (long)cti[p] * 25;
  for (int c = t; c < 448; c += 256) {
    u32 vl, vr;
    if (c < 100)      { vl = vr = tload2(charE,  c0 + c); }
    else if (c < 200) { vl = vr = tload2(extE,   e0 + c - 100); }
    else if (c < 300) { vl = tload2(biE,  lb0 + c - 200); vr = tload2(biE,  rb0 + c - 200); }
    else if (c < 400) { vl = tload2(extbiE, le0 + c - 300); vr = tload2(extbiE, re0 + c - 300); }
    else if (c < 425) { vl = vr = tload2(ctypeE, ct0 + c - 400); }
    else              { vl = vr = 0u; }
    L[c] = vl; R[c] = vr;
  }
}

// ======================= GEMM1: IN = tanh(cat @ Wlin^T + b) =======================
// M=65536, N=512, K=896. BM=BN=128, BK=64, 256 thr (4 waves, 2x2 of 64x64).
__global__ __launch_bounds__(256) void k_gemm1(
    const u16* __restrict__ cat, const u16* __restrict__ wlin,
    const void* __restrict__ blin, u16* __restrict__ IN) {
  __shared__ __align__(16) u16 As[128 * 64];
  __shared__ __align__(16) u16 Bs[128 * 64];
  const int tid = threadIdx.x, w = tid >> 6, l = tid & 63;
  const int m0 = blockIdx.x * 128, n0 = blockIdx.y * 128;
  const int wm = w >> 1, wn = w & 1;
  f32x4 acc[4][4] = {};
  for (int k0 = 0; k0 < KPAD; k0 += 64) {
    #pragma unroll
    for (int it = 0; it < 4; ++it) {
      int rw = it * 32 + w * 8;
      int row = rw + (l >> 3);
      int q = (l & 7) ^ (row & 7);                    // XOR-swizzled source chunk
      async16(cat  + (size_t)(m0 + row) * KPAD + k0 + q * 8, &As[rw * 64]);
      async16(wlin + (size_t)(n0 + row) * KPAD + k0 + q * 8, &Bs[rw * 64]);
    }
    __builtin_amdgcn_s_waitcnt(0);
    __syncthreads();
    #pragma unroll
    for (int kk = 0; kk < 2; ++kk) {
      bf16x8 av[4], bv[4];
      #pragma unroll
      for (int mt = 0; mt < 4; ++mt) {
        int row = wm * 64 + mt * 16 + (l & 15);
        int cg = kk * 4 + (l >> 4);
        av[mt] = *(const bf16x8*)&As[row * 64 + ((cg ^ (row & 7)) << 3)];
      }
      #pragma unroll
      for (int nt = 0; nt < 4; ++nt) {
        int row = wn * 64 + nt * 16 + (l & 15);
        int cg = kk * 4 + (l >> 4);
        bv[nt] = *(const bf16x8*)&Bs[row * 64 + ((cg ^ (row & 7)) << 3)];
      }
      #pragma unroll
      for (int mt = 0; mt < 4; ++mt)
        #pragma unroll
        for (int nt = 0; nt < 4; ++nt)
          acc[mt][nt] = __builtin_amdgcn_mfma_f32_16x16x32_bf16(av[mt], bv[nt], acc[mt][nt], 0, 0, 0);
    }
    __syncthreads();
  }
  #pragma unroll
  for (int nt = 0; nt < 4; ++nt) {
    int col = n0 + wn * 64 + nt * 16 + (l & 15);
    float bb = wloadf(blin, col);
    #pragma unroll
    for (int mt = 0; mt < 4; ++mt)
      #pragma unroll
      for (int r = 0; r < 4; ++r) {
        int row = m0 + wm * 64 + mt * 16 + (l >> 4) * 4 + r;
        IN[(size_t)row * 512 + col] = f2bf(tanhf(acc[mt][nt][r] + bb));
      }
  }
}

// ======================= GEMM2: xg[dir][s][b][n'] = IN @ Wih^T + b4 =======================
// per dir: M=32768, N=2048, K=512
__global__ __launch_bounds__(256) void k_gemm2(
    const u16* __restrict__ IN, const u16* __restrict__ wih,
    const float* __restrict__ b4, u16* __restrict__ xg) {
  __shared__ __align__(16) u16 As[128 * 64];
  __shared__ __align__(16) u16 Bs[128 * 64];
  const int tid = threadIdx.x, w = tid >> 6, l = tid & 63;
  const int m0 = blockIdx.x * 128, n0 = blockIdx.y * 128, dir = blockIdx.z;
  const int wm = w >> 1, wn = w & 1;
  f32x4 acc[4][4] = {};
  for (int k0 = 0; k0 < 512; k0 += 64) {
    #pragma unroll
    for (int it = 0; it < 4; ++it) {
      int rw = it * 32 + w * 8;
      int row = rw + (l >> 3);
      int q = (l & 7) ^ (row & 7);
      async16(IN  + (size_t)(dir * BS + m0 + row) * 512 + k0 + q * 8, &As[rw * 64]);
      async16(wih + (size_t)(dir * G4 + n0 + row) * 512 + k0 + q * 8, &Bs[rw * 64]);
    }
    __builtin_amdgcn_s_waitcnt(0);
    __syncthreads();
    #pragma unroll
    for (int kk = 0; kk < 2; ++kk) {
      bf16x8 av[4], bv[4];
      #pragma unroll
      for (int mt = 0; mt < 4; ++mt) {
        int row = wm * 64 + mt * 16 + (l & 15);
        int cg = kk * 4 + (l >> 4);
        av[mt] = *(const bf16x8*)&As[row * 64 + ((cg ^ (row & 7)) << 3)];
      }
      #pragma unroll
      for (int nt = 0; nt < 4; ++nt) {
        int row = wn * 64 + nt * 16 + (l & 15);
        int cg = kk * 4 + (l >> 4);
        bv[nt] = *(const bf16x8*)&Bs[row * 64 + ((cg ^ (row & 7)) << 3)];
      }
      #pragma unroll
      for (int mt = 0; mt < 4; ++mt)
        #pragma unroll
        for (int nt = 0; nt < 4; ++nt)
          acc[mt][nt] = __builtin_amdgcn_mfma_f32_16x16x32_bf16(av[mt], bv[nt], acc[mt][nt], 0, 0, 0);
    }
    __syncthreads();
  }
  #pragma unroll
  for (int nt = 0; nt < 4; ++nt) {
    int col = n0 + wn * 64 + nt * 16 + (l & 15);
    float bb = b4[dir * G4 + col];
    #pragma unroll
    for (int mt = 0; mt < 4; ++mt)
      #pragma unroll
      for (int r = 0; r < 4; ++r) {
        int pos = m0 + wm * 64 + mt * 16 + (l >> 4) * 4 + r;
        int s = pos & 511, b = pos >> 9;
        xg[(((size_t)dir * 512 + s) * 64 + b) * G4 + col] = f2bf(acc[mt][nt][r] + bb);
      }
  }
}

// ======================= persistent LSTM recurrence =======================
// 128 wgs = 4 independent chains keyed (dir, batch-half), 32 wgs (gate-chunks) each.
// W_hh slice pinned in 64 VGPRs/lane. Fence-free sync: all cross-wg data moves via
// relaxed agent-scope atomics (sc0/sc1 coherent, NO buffer_wbl2 / buffer_inv);
// ordering = s_waitcnt vmcnt(0) + barrier before publishing a per-wg step slot
// (canonical release: drain coherent stores, then coherent flag store).
__global__ __launch_bounds__(256) void k_rnn(
    const u16* __restrict__ xg, const u16* __restrict__ whh,
    u16* __restrict__ hbuf, u32* __restrict__ cnt, float* __restrict__ out) {
  __shared__ __align__(16) u16 Hs[32 * 520];     // 32 batch rows x 512 h (+8 pad shorts)
  __shared__ float garr[32 * 66];                // activated gates; stride 66: 16-way -> 4-way LDS conflict
  __shared__ float cs[32 * 16];                  // cell state (fp32, persistent)
  const int tid = threadIdx.x, w = tid >> 6, l = tid & 63;
  const int bid = blockIdx.x;
  const int dir = bid >> 6;
  const int sub = bid & 63;
  const int chunk = sub >> 1;
  const int half = sub & 1;
  const int b0 = half * 32;

  // preload W_hh slice: wave w owns gates [chunk*64 + w*16, +16)
  bf16x8 wf[16];
  const u16* wbase = whh + ((size_t)dir * G4 + chunk * 64 + w * 16 + (l & 15)) * 512;
  #pragma unroll
  for (int ks = 0; ks < 16; ++ks)
    wf[ks] = *(const bf16x8*)(wbase + ks * 32 + (l >> 4) * 8);

  for (int i = tid; i < 32 * 16; i += 256) cs[i] = 0.f;
  __syncthreads();

  // per-chain flag slots: chain (dir,half) owns 32 u32, one per gate-chunk wg
  u32* slots = cnt + (size_t)(dir * 2 + half) * 32;

  // prefetch xg for step 0
  u16 xr[2][4];
  {
    const int t0 = dir ? 511 : 0;
    const u16* a0 = xg + (((size_t)dir * 512 + t0) * 64 + b0) * G4 + chunk * 64 + w * 16 + (l & 15);
    #pragma unroll
    for (int mt = 0; mt < 2; ++mt)
      #pragma unroll
      for (int r = 0; r < 4; ++r)
        xr[mt][r] = a0[(size_t)(mt * 16 + (l >> 4) * 4 + r) * G4];
  }

  for (int p = 0; p < 512; ++p) {
    if (p > 0) {
      // wait: all 32 wgs of this chain finished step p-1 (slot value >= p).
      // busy-poll: the coherent load round-trip (~LLC latency) IS the poll period.
      if (tid < 32) {
        while (aload32(&slots[tid]) < (u32)p) { }
      }
      __syncthreads();
      asm volatile("" ::: "memory");
    }
    const int t_eff = dir ? (511 - p) : p;
    const int par = p & 1;

    // stage h_{t-1} slice (32 rows x 512) into LDS via coherent b64 loads
    const u16* hsrc = hbuf + ((size_t)(dir * 2 + par) * Bb + b0) * 512;
    #pragma unroll
    for (int it = 0; it < 8; ++it) {
      int row = w * 8 + it;
      const u64* src = (const u64*)(hsrc + (size_t)row * 512);
      u64 v0 = aload64(src + l * 2);
      u64 v1 = aload64(src + l * 2 + 1);
      u32x4 vv;
      vv.x = (u32)v0; vv.y = (u32)(v0 >> 32);
      vv.z = (u32)v1; vv.w = (u32)(v1 >> 32);
      *(u32x4*)&Hs[row * 520 + l * 8] = vv;     // contiguous 1KB per wave: conflict-free
    }
    __syncthreads();

    // GEMM: [32 x 512] @ [512 x 64-gates]; wave w = its 16-gate strip
    f32x4 acc2[2] = {};
    #pragma unroll
    for (int ks = 0; ks < 16; ++ks) {
      #pragma unroll
      for (int mt = 0; mt < 2; ++mt) {
        int row = mt * 16 + (l & 15);
        bf16x8 a = *(const bf16x8*)&Hs[row * 520 + ks * 32 + (l >> 4) * 8];
        acc2[mt] = __builtin_amdgcn_mfma_f32_16x16x32_bf16(a, wf[ks], acc2[mt], 0, 0, 0);
      }
    }

    // activate gates -> garr (gate type = n' & 3 = l & 3; 2 == tanh-gate)
    #pragma unroll
    for (int mt = 0; mt < 2; ++mt)
      #pragma unroll
      for (int r = 0; r < 4; ++r) {
        float g = acc2[mt][r] + bf2f(xr[mt][r]);
        int tp = l & 3;
        float v = (tp == 2) ? tanhf(g) : 1.f / (1.f + __expf(-g));
        garr[(mt * 16 + (l >> 4) * 4 + r) * 66 + w * 16 + (l & 15)] = v;
      }
    __syncthreads();

    // combine: thread = (batch row b, h-pair jp)
    float h0, h1;
    int b = tid >> 3, jp = tid & 7;
    {
      const float* gp = &garr[b * 66 + jp * 8];
      float i0 = gp[0], f0 = gp[1], g0 = gp[2], o0 = gp[3];
      float i1 = gp[4], f1 = gp[5], g1 = gp[6], o1 = gp[7];
      float c0v = f0 * cs[b * 16 + jp * 2]     + i0 * g0;
      float c1v = f1 * cs[b * 16 + jp * 2 + 1] + i1 * g1;
      cs[b * 16 + jp * 2] = c0v;
      cs[b * 16 + jp * 2 + 1] = c1v;
      h0 = o0 * tanhf(c0v); h1 = o1 * tanhf(c1v);
      u32 packed = (u32)f2bf(h0) | ((u32)f2bf(h1) << 16);
      astore32(&((u32*)hbuf)[(((size_t)(dir * 2 + (1 - par)) * Bb + b0 + b) * 512 + chunk * 16 + jp * 2) >> 1],
               packed);
    }

    // release: drain this wave's coherent h stores, wg-wide barrier, publish slot.
    // (out-stores deliberately NOT yet issued -> not part of the drain)
    asm volatile("s_waitcnt vmcnt(0)" ::: "memory");
    __syncthreads();
    if (tid == 0) astore32(&slots[chunk], (u32)(p + 1));

    // output store (nobody reads this cross-wg; overlaps with next poll)
    {
#if OUT_BF16
      u32 packed = (u32)f2bf(h0) | ((u32)f2bf(h1) << 16);
      ((u32*)out)[(((size_t)(b0 + b) * 512 + t_eff) * 1024 + dir * 512 + chunk * 16 + jp * 2) >> 1] = packed;
#else
      size_t oi = ((size_t)(b0 + b) * 512 + t_eff) * 1024 + dir * 512 + chunk * 16 + jp * 2;
      float2 o2; o2.x = h0; o2.y = h1;
      *(float2*)&out[oi] = o2;
#endif
    }

    // prefetch xg for step p+1 (independent of other wgs; hides HBM latency under poll)
    {
      int pn = (p < 511) ? (p + 1) : 511;
      int tn = dir ? (511 - pn) : pn;
      const u16* a2 = xg + (((size_t)dir * 512 + tn) * 64 + b0) * G4 + chunk * 64 + w * 16 + (l & 15);
      #pragma unroll
      for (int mt = 0; mt < 2; ++mt)
        #pragma unroll
        for (int r = 0; r < 4; ++r)
          xr[mt][r] = a2[(size_t)(mt * 16 + (l >> 4) * 4 + r) * G4];
    }
  }
}

// ======================= launch =======================
extern "C" void kernel_launch(void* const* d_in, const int* in_sizes, int n_in,
                              void* d_out, int out_size, void* d_ws, size_t ws_size,
                              hipStream_t stream) {
  if (ws_size < WS_NEED) return;   // would corrupt; fail visibly (output stays zero)
  char* ws = (char*)d_ws;
  u16*   cat_h = (u16*)(ws + OFF_CAT);
  u16*   wlin  = (u16*)(ws + OFF_WLIN);
  u16*   wih   = (u16*)(ws + OFF_WIH);
  u16*   whh   = (u16*)(ws + OFF_WHH);
  float* b4    = (float*)(ws + OFF_B4);
  u16*   IN    = (u16*)(ws + OFF_IN);
  u16*   xgb   = (u16*)(ws + OFF_XG);
  u16*   hbuf  = (u16*)(ws + OFF_HBUF);
  u32*   cnt   = (u32*)(ws + OFF_CNT);

  k_prep<<<18708, 256, 0, stream>>>(
      d_in[12], d_in[14], d_in[15], d_in[16], d_in[17],
      d_in[18], d_in[19], d_in[20], d_in[21],
      wlin, wih, whh, b4, hbuf, cnt);

  k_gather<<<BS, 256, 0, stream>>>(
      (const int*)d_in[0], (const int*)d_in[1], (const int*)d_in[2], (const int*)d_in[3],
      (const int*)d_in[4], (const int*)d_in[5], (const int*)d_in[6],
      d_in[7], d_in[8], d_in[9], d_in[10], d_in[11], (u32*)cat_h);

  k_gemm1<<<dim3(512, 4), 256, 0, stream>>>(cat_h, wlin, d_in[13], IN);

  k_gemm2<<<dim3(256, 16, 2), 256, 0, stream>>>(IN, wih, b4, xgb);

  k_rnn<<<128, 256, 0, stream>>>(xgb, whh, hbuf, cnt, (float*)d_out);
}